// Round 1
// baseline (154.838 us; speedup 1.0000x reference)
//
#include <hip/hip_runtime.h>
#include <hip/hip_bf16.h>

typedef __attribute__((ext_vector_type(4)))  float f32x4;
typedef __attribute__((ext_vector_type(16))) float f32x16;
typedef __attribute__((ext_vector_type(8)))  short bf16x8;

__device__ __forceinline__ short f2bf(float x){
    __hip_bfloat16 h = __float2bfloat16(x);
    return __builtin_bit_cast(short, h);
}
__device__ __forceinline__ float bf2f(short x){
    unsigned int u = ((unsigned int)(unsigned short)x) << 16;
    return __builtin_bit_cast(float, u);
}

// ---------------------------------------------------------------- pre kernel
// blocks 0..255   : dense scores (16 docs x 32 q each, f32x4 inner loop) + sparse copy
// blocks 256..511 : Bws(bf16)[16 doc rows] = doc @ W1b
// blocks 512..513 : Aq(f32)[16 q rows]     = query @ W1a + b1
// block  514      : W1cdf f32 table [768]: [0..383]=W1[768][:] (dense), [384..767]=W1[769][:] (sparse)
// blocks 515..518 : W2t = W2 in bf16, pre-tiled in the exact 32x32-frag chunk order main's LDS
//                   wants: chunk c=(s*6+t2)*64+lane_c holds W2[k][n], n=t2*32+(lane_c&31),
//                   k=s*16+((lane_c>>5)&1)*8+j  -> main stages it with a LINEAR copy (no VALU).
__global__ __launch_bounds__(256)
void pre_kernel(const float* __restrict__ query, const float* __restrict__ doc,
                const float* __restrict__ sparse, const float* __restrict__ W1,
                const float* __restrict__ b1, const float* __restrict__ W2,
                float* __restrict__ out_dense, float* __restrict__ out_sparse,
                short* __restrict__ Bws, float* __restrict__ Aq,
                float* __restrict__ W1cdf, short* __restrict__ W2t){
    __shared__ float ldsq[32*388];
    __shared__ float ldsd[16*388];
    const int b = blockIdx.x, tid = threadIdx.x;

    if (b < 256){
        const int d0 = b*16;
        #pragma unroll
        for (int i=0;i<12;i++){ int idx = tid + i*256; int row = idx/96, c4 = idx%96;
            *(f32x4*)(ldsq + row*388 + c4*4) = *(const f32x4*)(query + row*384 + c4*4); }
        #pragma unroll
        for (int i=0;i<6;i++){ int idx = tid + i*256; int row = idx/96, c4 = idx%96;
            *(f32x4*)(ldsd + row*388 + c4*4) = *(const f32x4*)(doc + (d0+row)*384 + c4*4); }
        __syncthreads();
        const int q = tid>>3, dg = tid&7;
        const f32x4* q4  = (const f32x4*)(ldsq + q*388);
        const f32x4* d4a = (const f32x4*)(ldsd + dg*388);
        const f32x4* d4b = (const f32x4*)(ldsd + (dg+8)*388);
        f32x4 s0 = {0.f,0.f,0.f,0.f}, s1 = {0.f,0.f,0.f,0.f};
        #pragma unroll 4
        for (int k=0;k<96;k++){
            const f32x4 qv = q4[k];
            s0 += qv*d4a[k];
            s1 += qv*d4b[k];
        }
        out_dense[q*4096 + d0 + dg]     = s0[0]+s0[1]+s0[2]+s0[3];
        out_dense[q*4096 + d0 + dg + 8] = s1[0]+s1[1]+s1[2]+s1[3];
        if (tid < 128){
            int qq = tid>>2, c4 = tid&3;
            *(f32x4*)(out_sparse + qq*4096 + d0 + c4*4) = *(const f32x4*)(sparse + qq*4096 + d0 + c4*4);
        }
    } else if (b < 514){
        const int bb = b - 256;
        const int w = tid >> 6, lane = tid & 63;
        const int cl = lane & 15, quad = lane >> 4;
        const float* src; const float* wrow; int r0; bool isA;
        if (bb < 256){ r0 = bb*16;       src = doc;   wrow = W1 + 384*384; isA = false; }
        else         { r0 = (bb-256)*16; src = query; wrow = W1;           isA = true;  }

        f32x4 acc[6];
        #pragma unroll
        for (int t=0;t<6;t++) acc[t] = (f32x4){0.f,0.f,0.f,0.f};

        #pragma unroll 1
        for (int s=0;s<12;s++){
            const float* ap = src + (r0+cl)*384 + s*32 + quad*8;
            const f32x4 a0 = *(const f32x4*)ap;
            const f32x4 a1 = *(const f32x4*)(ap+4);
            bf16x8 af;
            #pragma unroll
            for (int j=0;j<4;j++){ af[j] = f2bf(a0[j]); af[4+j] = f2bf(a1[j]); }
            const float* wk = wrow + (s*32 + quad*8)*384;
            #pragma unroll
            for (int tt=0;tt<6;tt++){
                const int col = (w*6+tt)*16 + cl;
                bf16x8 bf_;
                #pragma unroll
                for (int j=0;j<8;j++) bf_[j] = f2bf(wk[j*384 + col]);
                acc[tt] = __builtin_amdgcn_mfma_f32_16x16x32_bf16(af, bf_, acc[tt], 0, 0, 0);
            }
        }
        #pragma unroll
        for (int tt=0;tt<6;tt++){
            const int col = (w*6+tt)*16 + cl;
            if (isA){
                const float b1v = b1[col];
                #pragma unroll
                for (int r=0;r<4;r++)
                    Aq[(r0 + quad*4 + r)*384 + col] = acc[tt][r] + b1v;
            } else {
                #pragma unroll
                for (int r=0;r<4;r++)
                    Bws[(r0 + quad*4 + r)*384 + col] = f2bf(acc[tt][r]);
            }
        }
    } else if (b == 514){
        #pragma unroll
        for (int i=0;i<3;i++){
            int o = tid + i*256;                     // < 768
            W1cdf[o] = (o < 384) ? W1[768*384 + o] : W1[769*384 + (o - 384)];
        }
    } else {
        // W2 bf16 tiling: 4 blocks x 256 thr = 1024 lanes, 9 chunks each -> 9216 chunks
        const int t0 = (b - 515)*256 + tid;
        #pragma unroll
        for (int i=0;i<9;i++){
            int c = t0 + i*1024;                     // < 9216
            int lane_c = c & 63, st = c >> 6;        // st < 144
            int s = st/6, t2 = st%6;
            int n = t2*32 + (lane_c&31), kb = s*16 + ((lane_c>>5)&1)*8;
            bf16x8 v;
            #pragma unroll
            for (int j=0;j<8;j++) v[j] = f2bf(W2[(kb+j)*192 + n]);
            *(bf16x8*)(W2t + c*8) = v;
        }
    }
}

// ---------------------------------------------------------------- main fused MLP kernel
// 256 blocks x 1024 thr = 16 waves, 1 block/CU (LDS 152.6 KB) -> 4 waves/SIMD (vs 2 before).
// N-split: each doc column is owned by TWO waves (ngrp = w>>3); each wave accumulates only
// 3 n-tiles -> acc = 3 x f32x16 = 48 regs, total ~115/wave, fits the 128-reg budget of
// __launch_bounds__(1024,4). Per-wave LDS B-frag reads halve (3/step). W1cd lives in LDS as
// f32 (off the vmcnt critical path; no bf2f). W2 arrives pre-tiled bf16 (W2t) so staging is a
// pure linear f32x4 copy. Layer-3 partials of the two n-groups combine via 2 KB LDS scratch.
// A-frag: m=lane&31, k=(lane>>5)*8+j.  B-frag: n=lane&31, same k.
// C/D: col=lane&31, row=(reg&3)+8*(reg>>2)+4*(lane>>5)  [m74/m101-verified].
__global__ __launch_bounds__(1024, 4)
void main_kernel(const float* __restrict__ Aq, const short* __restrict__ Bws,
                 const float* __restrict__ W1cdf, const short* __restrict__ W2t,
                 const float* __restrict__ b2, const float* __restrict__ W3,
                 const float* __restrict__ b3, const float* __restrict__ sparse,
                 const float* __restrict__ dense_in, float* __restrict__ out_final){
    __shared__ __align__(16) short lw[73728];        // 147,456 B  W2 bf16 tiled
    __shared__ __align__(16) float lcd[768];         //   3,072 B  [0..383]=W1c, [384..767]=W1d
    __shared__ float lred[512];                      //   2,048 B  layer-3 partials
    const int tid = threadIdx.x;

    // stage W2t -> LDS (linear copy, no conversions) and W1cdf -> LDS
    #pragma unroll
    for (int i=0;i<9;i++){
        int c = tid + i*1024;
        *(f32x4*)(lw + c*8) = *(const f32x4*)(W2t + c*8);
    }
    if (tid < 192)
        *(f32x4*)(lcd + tid*4) = *(const f32x4*)(W1cdf + tid*4);
    __syncthreads();                                 // only staging barrier

    const int lane = tid & 63, w = tid >> 6;
    const int wc = w & 7, ngrp = w >> 3;             // col slot / n-group
    const int m = lane & 31, q2 = lane >> 5;         // row m; k-half q2
    const int kbase = q2*8;
    const float b3v = b3[0];

    #pragma unroll 1
    for (int t4=0; t4<2; t4++){
        const int dcol = blockIdx.x*16 + t4*8 + wc;  // doc column, < 4096
        const float dsv = dense_in[m*4096 + dcol];
        const float ssv = sparse[m*4096 + dcol];

        f32x16 acc[3];
        #pragma unroll
        for (int t=0;t<3;t++)
            #pragma unroll
            for (int r=0;r<16;r++) acc[t][r] = 0.0f;

        // prefetch s=0
        bf16x8 bw_c = *(const bf16x8*)(Bws + dcol*384 + kbase);
        f32x4  a0_c = *(const f32x4*)(Aq + m*384 + kbase);
        f32x4  a1_c = *(const f32x4*)(Aq + m*384 + kbase + 4);

        #pragma unroll 1
        for (int s=0;s<24;s++){
            const int k0 = s*16 + kbase;
            const int kn = (s < 23) ? (k0 + 16) : kbase;     // dummy wrap on last iter
            const bf16x8 bw_n = *(const bf16x8*)(Bws + dcol*384 + kn);
            const f32x4  a0_n = *(const f32x4*)(Aq + m*384 + kn);
            const f32x4  a1_n = *(const f32x4*)(Aq + m*384 + kn + 4);
            const f32x4 wc0 = *(const f32x4*)(lcd + k0);
            const f32x4 wc1 = *(const f32x4*)(lcd + k0 + 4);
            const f32x4 wd0 = *(const f32x4*)(lcd + 384 + k0);
            const f32x4 wd1 = *(const f32x4*)(lcd + 384 + k0 + 4);
            bf16x8 fr;
            #pragma unroll
            for (int j=0;j<4;j++){
                float h0 = a0_c[j] + bf2f(bw_c[j])   + dsv*wc0[j] + ssv*wd0[j];
                float h1 = a1_c[j] + bf2f(bw_c[4+j]) + dsv*wc1[j] + ssv*wd1[j];
                fr[j]   = f2bf(fmaxf(h0, 0.0f));
                fr[4+j] = f2bf(fmaxf(h1, 0.0f));
            }
            #pragma unroll
            for (int tt=0;tt<3;tt++){
                const int t = ngrp*3 + tt;
                const bf16x8 bfr = *(const bf16x8*)(lw + ((s*6 + t)*64 + lane)*8);
                acc[tt] = __builtin_amdgcn_mfma_f32_32x32x16_bf16(fr, bfr, acc[tt], 0, 0, 0);
            }
            bw_c = bw_n; a0_c = a0_n; a1_c = a1_n;
        }

        // layer 3 partial over this wave's 96 n: p[r] = sum_n relu(h2+b2)*W3
        float p[16];
        #pragma unroll
        for (int r=0;r<16;r++) p[r] = 0.0f;
        #pragma unroll
        for (int tt=0;tt<3;tt++){
            const int n = (ngrp*3 + tt)*32 + m;
            const float b2v = b2[n];
            const float w3v = W3[n];
            #pragma unroll
            for (int r=0;r<16;r++)
                p[r] += fmaxf(acc[tt][r] + b2v, 0.0f) * w3v;
        }
        // reduce over the 32 lanes of this q2 half
        #pragma unroll
        for (int mask=1; mask<32; mask<<=1){
            #pragma unroll
            for (int r=0;r<16;r++) p[r] += __shfl_xor(p[r], mask);
        }
        // lane m<16 takes p[m] (static cndmask chain; no dynamic reg indexing)
        float myp = p[0];
        #pragma unroll
        for (int r=1;r<16;r++) myp = (m==r) ? p[r] : myp;
        if (m < 16){
            const int row = (m&3) + 8*(m>>2) + 4*q2;
            lred[wc*64 + row*2 + ngrp] = myp;
        }
        __syncthreads();
        if (tid < 256){
            const int cl = tid >> 5, row = tid & 31;
            const float logit = lred[cl*64 + row*2] + lred[cl*64 + row*2 + 1] + b3v;
            const float wgt = 1.0f/(1.0f + __expf(-logit));
            const int dc = blockIdx.x*16 + t4*8 + cl;
            const float dd = dense_in[row*4096 + dc];
            const float ss = sparse[row*4096 + dc];
            out_final[row*4096 + dc] = wgt*dd + (1.0f - wgt)*ss;
        }
        __syncthreads();                             // protect lred reuse in t4=1
    }
}

// ---------------------------------------------------------------- launch
extern "C" void kernel_launch(void* const* d_in, const int* in_sizes, int n_in,
                              void* d_out, int out_size, void* d_ws, size_t ws_size,
                              hipStream_t stream){
    const float* query  = (const float*)d_in[0];
    const float* doc    = (const float*)d_in[1];
    const float* sparse = (const float*)d_in[2];
    const float* W1     = (const float*)d_in[3];
    const float* b1     = (const float*)d_in[4];
    const float* W2     = (const float*)d_in[5];
    const float* b2     = (const float*)d_in[6];
    const float* W3     = (const float*)d_in[7];
    const float* b3     = (const float*)d_in[8];

    float* out_final  = (float*)d_out;                 // [32,4096]
    float* out_dense  = (float*)d_out + 131072;        // [32,4096]
    float* out_sparse = (float*)d_out + 262144;        // [32,4096]

    // workspace layout (16B-aligned), total 3,345,408 B
    short* Bws   = (short*)d_ws;                                  // 3,145,728 B  (bf16 [4096][384])
    float* Aq    = (float*)((char*)d_ws + 3145728);               //    49,152 B  (f32  [32][384])
    float* W1cdf = (float*)((char*)d_ws + 3194880);               //     3,072 B  (f32  [768])
    short* W2t   = (short*)((char*)d_ws + 3197952);               //   147,456 B  (bf16 tiled W2)

    hipLaunchKernelGGL(pre_kernel,  dim3(519), dim3(256), 0, stream,
                       query, doc, sparse, W1, b1, W2, out_dense, out_sparse, Bws, Aq, W1cdf, W2t);
    hipLaunchKernelGGL(main_kernel, dim3(256), dim3(1024), 0, stream,
                       Aq, Bws, W1cdf, W2t, b2, W3, b3, sparse, out_dense, out_final);
}

// Round 2
// 128.157 us; speedup vs baseline: 1.2082x; 1.2082x over previous
//
#include <hip/hip_runtime.h>
#include <hip/hip_bf16.h>

typedef __attribute__((ext_vector_type(2)))  float f32x2;
typedef __attribute__((ext_vector_type(4)))  float f32x4;
typedef __attribute__((ext_vector_type(16))) float f32x16;
typedef __attribute__((ext_vector_type(8)))  short bf16x8;
typedef __attribute__((ext_vector_type(4)))  unsigned int u32x4;

__device__ __forceinline__ short f2bf(float x){
    __hip_bfloat16 h = __float2bfloat16(x);
    return __builtin_bit_cast(short, h);
}
__device__ __forceinline__ float bf2f(short x){
    unsigned int u = ((unsigned int)(unsigned short)x) << 16;
    return __builtin_bit_cast(float, u);
}
// one packed RNE convert for a bf16 pair (T12 recipe; non-volatile so the scheduler may move it)
__device__ __forceinline__ unsigned int cvt2(float lo, float hi){
    unsigned int r;
    asm("v_cvt_pk_bf16_f32 %0, %1, %2" : "=v"(r) : "v"(lo), "v"(hi));
    return r;
}

// ---------------------------------------------------------------- pre kernel (unchanged from r1)
// blocks 0..255   : dense scores (16 docs x 32 q each, f32x4 inner loop) + sparse copy
// blocks 256..511 : Bws(bf16)[16 doc rows] = doc @ W1b
// blocks 512..513 : Aq(f32)[16 q rows]     = query @ W1a + b1
// block  514      : W1cdf f32 table [768]: [0..383]=W1[768][:] (dense), [384..767]=W1[769][:] (sparse)
// blocks 515..518 : W2t = W2 bf16 pre-tiled in main's 32x32-frag chunk order
__global__ __launch_bounds__(256)
void pre_kernel(const float* __restrict__ query, const float* __restrict__ doc,
                const float* __restrict__ sparse, const float* __restrict__ W1,
                const float* __restrict__ b1, const float* __restrict__ W2,
                float* __restrict__ out_dense, float* __restrict__ out_sparse,
                short* __restrict__ Bws, float* __restrict__ Aq,
                float* __restrict__ W1cdf, short* __restrict__ W2t){
    __shared__ float ldsq[32*388];
    __shared__ float ldsd[16*388];
    const int b = blockIdx.x, tid = threadIdx.x;

    if (b < 256){
        const int d0 = b*16;
        #pragma unroll
        for (int i=0;i<12;i++){ int idx = tid + i*256; int row = idx/96, c4 = idx%96;
            *(f32x4*)(ldsq + row*388 + c4*4) = *(const f32x4*)(query + row*384 + c4*4); }
        #pragma unroll
        for (int i=0;i<6;i++){ int idx = tid + i*256; int row = idx/96, c4 = idx%96;
            *(f32x4*)(ldsd + row*388 + c4*4) = *(const f32x4*)(doc + (d0+row)*384 + c4*4); }
        __syncthreads();
        const int q = tid>>3, dg = tid&7;
        const f32x4* q4  = (const f32x4*)(ldsq + q*388);
        const f32x4* d4a = (const f32x4*)(ldsd + dg*388);
        const f32x4* d4b = (const f32x4*)(ldsd + (dg+8)*388);
        f32x4 s0 = {0.f,0.f,0.f,0.f}, s1 = {0.f,0.f,0.f,0.f};
        #pragma unroll 4
        for (int k=0;k<96;k++){
            const f32x4 qv = q4[k];
            s0 += qv*d4a[k];
            s1 += qv*d4b[k];
        }
        out_dense[q*4096 + d0 + dg]     = s0[0]+s0[1]+s0[2]+s0[3];
        out_dense[q*4096 + d0 + dg + 8] = s1[0]+s1[1]+s1[2]+s1[3];
        if (tid < 128){
            int qq = tid>>2, c4 = tid&3;
            *(f32x4*)(out_sparse + qq*4096 + d0 + c4*4) = *(const f32x4*)(sparse + qq*4096 + d0 + c4*4);
        }
    } else if (b < 514){
        const int bb = b - 256;
        const int w = tid >> 6, lane = tid & 63;
        const int cl = lane & 15, quad = lane >> 4;
        const float* src; const float* wrow; int r0; bool isA;
        if (bb < 256){ r0 = bb*16;       src = doc;   wrow = W1 + 384*384; isA = false; }
        else         { r0 = (bb-256)*16; src = query; wrow = W1;           isA = true;  }

        f32x4 acc[6];
        #pragma unroll
        for (int t=0;t<6;t++) acc[t] = (f32x4){0.f,0.f,0.f,0.f};

        #pragma unroll 1
        for (int s=0;s<12;s++){
            const float* ap = src + (r0+cl)*384 + s*32 + quad*8;
            const f32x4 a0 = *(const f32x4*)ap;
            const f32x4 a1 = *(const f32x4*)(ap+4);
            bf16x8 af;
            #pragma unroll
            for (int j=0;j<4;j++){ af[j] = f2bf(a0[j]); af[4+j] = f2bf(a1[j]); }
            const float* wk = wrow + (s*32 + quad*8)*384;
            #pragma unroll
            for (int tt=0;tt<6;tt++){
                const int col = (w*6+tt)*16 + cl;
                bf16x8 bf_;
                #pragma unroll
                for (int j=0;j<8;j++) bf_[j] = f2bf(wk[j*384 + col]);
                acc[tt] = __builtin_amdgcn_mfma_f32_16x16x32_bf16(af, bf_, acc[tt], 0, 0, 0);
            }
        }
        #pragma unroll
        for (int tt=0;tt<6;tt++){
            const int col = (w*6+tt)*16 + cl;
            if (isA){
                const float b1v = b1[col];
                #pragma unroll
                for (int r=0;r<4;r++)
                    Aq[(r0 + quad*4 + r)*384 + col] = acc[tt][r] + b1v;
            } else {
                #pragma unroll
                for (int r=0;r<4;r++)
                    Bws[(r0 + quad*4 + r)*384 + col] = f2bf(acc[tt][r]);
            }
        }
    } else if (b == 514){
        #pragma unroll
        for (int i=0;i<3;i++){
            int o = tid + i*256;                     // < 768
            W1cdf[o] = (o < 384) ? W1[768*384 + o] : W1[769*384 + (o - 384)];
        }
    } else {
        // W2 bf16 tiling for 32x32x16 frags: chunk c=(s*6+t2)*64+lane_c, n=t2*32+(lane_c&31),
        // k=s*16+((lane_c>>5)&1)*8+j
        const int t0 = (b - 515)*256 + tid;
        #pragma unroll
        for (int i=0;i<9;i++){
            int c = t0 + i*1024;                     // < 9216
            int lane_c = c & 63, st = c >> 6;        // st < 144
            int s = st/6, t2 = st%6;
            int n = t2*32 + (lane_c&31), kb = s*16 + ((lane_c>>5)&1)*8;
            bf16x8 v;
            #pragma unroll
            for (int j=0;j<8;j++) v[j] = f2bf(W2[(kb+j)*192 + n]);
            *(bf16x8*)(W2t + c*8) = v;
        }
    }
}

// ---------------------------------------------------------------- main fused MLP kernel
// Round-0 structure restored: 256 blocks x 512 thr = 8 waves, 1 block/CU, one wave owns a doc
// column x all 32 q x all 192 n (6 x 32x32x16 tiles, acc = 96 AGPRs). Zero barriers after stage.
// Fixes vs round-0:
//  * W1c/W1d in LDS as f32 (lcd) -> the per-step broadcast read is on lgkmcnt, NOT vmcnt; the
//    round-0 in-step GLOBAL wcv/wdv load serialized every step behind the prefetches (in-order
//    vmcnt) = full L3 latency x 48 steps. That was the dominant stall.
//  * depth-3 prefetch (A/B/C slots) of Bws/Aq -> ~2.7 steps (~800 cy) latency coverage.
//  * fr-build on f32x2 pairs + v_cvt_pk_bf16_f32 (4 converts/step, fr assembled as packed
//    dwords) -> kills the software-RNE + element-insert VALU bloat.
//  * W2 arrives pre-tiled (W2t): staging is a pure linear f32x4 copy.
// A-frag: m=lane&31, k=(lane>>5)*8+j.  B-frag: n=lane&31, same k.
// C/D: col=lane&31, row=(reg&3)+8*(reg>>2)+4*(lane>>5)  [m74/m101-verified].
#define STEP(BW,A0,A1,S) do{                                                        \
    const int kf_ = (S)*16 + kbase;                                                 \
    const f32x4 wcA = *(const f32x4*)(lcd + kf_);                                   \
    const f32x4 wcB = *(const f32x4*)(lcd + kf_ + 4);                               \
    const f32x4 wdA = *(const f32x4*)(lcd + 384 + kf_);                             \
    const f32x4 wdB = *(const f32x4*)(lcd + 384 + kf_ + 4);                         \
    const short* lp_ = lw + ((S)*384 + lane)*8;                                     \
    const bf16x8 bfr0 = *(const bf16x8*)(lp_);                                      \
    const bf16x8 bfr1 = *(const bf16x8*)(lp_ + 512);                                \
    const bf16x8 bfr2 = *(const bf16x8*)(lp_ + 1024);                               \
    const bf16x8 bfr3 = *(const bf16x8*)(lp_ + 1536);                               \
    const bf16x8 bfr4 = *(const bf16x8*)(lp_ + 2048);                               \
    const bf16x8 bfr5 = *(const bf16x8*)(lp_ + 2560);                               \
    u32x4 frw_;                                                                     \
    { f32x2 h = {A0[0] + bf2f(BW[0]), A0[1] + bf2f(BW[1])};                         \
      h += dsv2 * (f32x2){wcA[0],wcA[1]}; h += ssv2 * (f32x2){wdA[0],wdA[1]};       \
      frw_[0] = cvt2(fmaxf(h[0],0.f), fmaxf(h[1],0.f)); }                           \
    { f32x2 h = {A0[2] + bf2f(BW[2]), A0[3] + bf2f(BW[3])};                         \
      h += dsv2 * (f32x2){wcA[2],wcA[3]}; h += ssv2 * (f32x2){wdA[2],wdA[3]};       \
      frw_[1] = cvt2(fmaxf(h[0],0.f), fmaxf(h[1],0.f)); }                           \
    { f32x2 h = {A1[0] + bf2f(BW[4]), A1[1] + bf2f(BW[5])};                         \
      h += dsv2 * (f32x2){wcB[0],wcB[1]}; h += ssv2 * (f32x2){wdB[0],wdB[1]};       \
      frw_[2] = cvt2(fmaxf(h[0],0.f), fmaxf(h[1],0.f)); }                           \
    { f32x2 h = {A1[2] + bf2f(BW[6]), A1[3] + bf2f(BW[7])};                         \
      h += dsv2 * (f32x2){wcB[2],wcB[3]}; h += ssv2 * (f32x2){wdB[2],wdB[3]};       \
      frw_[3] = cvt2(fmaxf(h[0],0.f), fmaxf(h[1],0.f)); }                           \
    const bf16x8 fr_ = __builtin_bit_cast(bf16x8, frw_);                            \
    acc[0] = __builtin_amdgcn_mfma_f32_32x32x16_bf16(fr_, bfr0, acc[0], 0, 0, 0);   \
    acc[1] = __builtin_amdgcn_mfma_f32_32x32x16_bf16(fr_, bfr1, acc[1], 0, 0, 0);   \
    acc[2] = __builtin_amdgcn_mfma_f32_32x32x16_bf16(fr_, bfr2, acc[2], 0, 0, 0);   \
    acc[3] = __builtin_amdgcn_mfma_f32_32x32x16_bf16(fr_, bfr3, acc[3], 0, 0, 0);   \
    acc[4] = __builtin_amdgcn_mfma_f32_32x32x16_bf16(fr_, bfr4, acc[4], 0, 0, 0);   \
    acc[5] = __builtin_amdgcn_mfma_f32_32x32x16_bf16(fr_, bfr5, acc[5], 0, 0, 0);   \
  }while(0)

__global__ __launch_bounds__(512, 2)
void main_kernel(const float* __restrict__ Aq, const short* __restrict__ Bws,
                 const float* __restrict__ W1cdf, const short* __restrict__ W2t,
                 const float* __restrict__ b2, const float* __restrict__ W3,
                 const float* __restrict__ b3, const float* __restrict__ sparse,
                 const float* __restrict__ dense_in, float* __restrict__ out_final){
    __shared__ __align__(16) short lw[73728];        // 147,456 B  W2 bf16 tiled
    __shared__ __align__(16) float lcd[768];         //   3,072 B  [0..383]=W1c, [384..767]=W1d
    const int tid = threadIdx.x;

    #pragma unroll
    for (int i=0;i<18;i++){
        int c = tid + i*512;
        *(f32x4*)(lw + c*8) = *(const f32x4*)(W2t + c*8);
    }
    if (tid < 192)
        *(f32x4*)(lcd + tid*4) = *(const f32x4*)(W1cdf + tid*4);
    __syncthreads();                                 // only barrier in the kernel

    const int lane = tid & 63, w = tid >> 6;
    const int m = lane & 31, q2 = lane >> 5;         // row m; k-half q2
    const int kbase = q2*8;
    const float b3v = b3[0];
    const int dcol0 = blockIdx.x*16 + w;

    // hoist per-column scalars for both t4 iterations (off the loop-boundary critical path)
    const float dsv0 = dense_in[m*4096 + dcol0];
    const float ssv0 = sparse[m*4096 + dcol0];
    const float dsv1 = dense_in[m*4096 + dcol0 + 8];
    const float ssv1 = sparse[m*4096 + dcol0 + 8];

    #pragma unroll 1
    for (int t4=0; t4<2; t4++){
        const int dcol = dcol0 + t4*8;
        const float dsv = t4 ? dsv1 : dsv0;
        const float ssv = t4 ? ssv1 : ssv0;
        const f32x2 dsv2 = {dsv, dsv}, ssv2 = {ssv, ssv};

        f32x16 acc[6];
        #pragma unroll
        for (int t=0;t<6;t++)
            #pragma unroll
            for (int r=0;r<16;r++) acc[t][r] = 0.0f;

        const short* bp = Bws + dcol*384;
        const float* ap = Aq + m*384;

        // depth-3 prefetch: slots A(s), B(s+1), C(s+2)
        bf16x8 bwA = *(const bf16x8*)(bp + kbase);
        f32x4  aA0 = *(const f32x4*)(ap + kbase);
        f32x4  aA1 = *(const f32x4*)(ap + kbase + 4);
        bf16x8 bwB = *(const bf16x8*)(bp + 16 + kbase);
        f32x4  aB0 = *(const f32x4*)(ap + 16 + kbase);
        f32x4  aB1 = *(const f32x4*)(ap + 16 + kbase + 4);
        bf16x8 bwC = *(const bf16x8*)(bp + 32 + kbase);
        f32x4  aC0 = *(const f32x4*)(ap + 32 + kbase);
        f32x4  aC1 = *(const f32x4*)(ap + 32 + kbase + 4);

        #pragma unroll 1
        for (int s=0; s<24; s+=3){
            STEP(bwA, aA0, aA1, s);
            { const int kp = (s+3 < 24) ? (s+3)*16 + kbase : kbase;   // dummy wrap at tail
              bwA = *(const bf16x8*)(bp + kp);
              aA0 = *(const f32x4*)(ap + kp);
              aA1 = *(const f32x4*)(ap + kp + 4); }
            STEP(bwB, aB0, aB1, s+1);
            { const int kp = (s+4 < 24) ? (s+4)*16 + kbase : kbase;
              bwB = *(const bf16x8*)(bp + kp);
              aB0 = *(const f32x4*)(ap + kp);
              aB1 = *(const f32x4*)(ap + kp + 4); }
            STEP(bwC, aC0, aC1, s+2);
            { const int kp = (s+5 < 24) ? (s+5)*16 + kbase : kbase;
              bwC = *(const bf16x8*)(bp + kp);
              aC0 = *(const f32x4*)(ap + kp);
              aC1 = *(const f32x4*)(ap + kp + 4); }
        }

        // layer 3: p[r] = sum_n relu(h2[row_r][n]+b2[n])*W3[n]; this lane covers n = t*32+m
        float p[16];
        #pragma unroll
        for (int r=0;r<16;r++) p[r] = 0.0f;
        #pragma unroll
        for (int t=0;t<6;t++){
            const int n = t*32 + m;
            const float b2v = b2[n];
            const float w3v = W3[n];
            #pragma unroll
            for (int r=0;r<16;r++)
                p[r] += fmaxf(acc[t][r] + b2v, 0.0f) * w3v;
        }
        // reduce over the 32 lanes of this q2 half (masks 1..16 stay within the half)
        #pragma unroll
        for (int mask=1; mask<32; mask<<=1){
            #pragma unroll
            for (int r=0;r<16;r++) p[r] += __shfl_xor(p[r], mask);
        }
        // lane m<16 takes p[m] (static cndmask chain; no dynamic reg indexing)
        float myp = p[0];
        #pragma unroll
        for (int r=1;r<16;r++) myp = (m==r) ? p[r] : myp;
        if (m < 16){
            const int row = (m&3) + 8*(m>>2) + 4*q2;
            float logit = myp + b3v;
            float wgt = 1.0f/(1.0f + __expf(-logit));
            float dd = dense_in[row*4096 + dcol];
            float ss = sparse[row*4096 + dcol];
            out_final[row*4096 + dcol] = wgt*dd + (1.0f - wgt)*ss;
        }
    }
}

// ---------------------------------------------------------------- launch
extern "C" void kernel_launch(void* const* d_in, const int* in_sizes, int n_in,
                              void* d_out, int out_size, void* d_ws, size_t ws_size,
                              hipStream_t stream){
    const float* query  = (const float*)d_in[0];
    const float* doc    = (const float*)d_in[1];
    const float* sparse = (const float*)d_in[2];
    const float* W1     = (const float*)d_in[3];
    const float* b1     = (const float*)d_in[4];
    const float* W2     = (const float*)d_in[5];
    const float* b2     = (const float*)d_in[6];
    const float* W3     = (const float*)d_in[7];
    const float* b3     = (const float*)d_in[8];

    float* out_final  = (float*)d_out;                 // [32,4096]
    float* out_dense  = (float*)d_out + 131072;        // [32,4096]
    float* out_sparse = (float*)d_out + 262144;        // [32,4096]

    // workspace layout (16B-aligned), total 3,345,408 B
    short* Bws   = (short*)d_ws;                                  // 3,145,728 B  (bf16 [4096][384])
    float* Aq    = (float*)((char*)d_ws + 3145728);               //    49,152 B  (f32  [32][384])
    float* W1cdf = (float*)((char*)d_ws + 3194880);               //     3,072 B  (f32  [768])
    short* W2t   = (short*)((char*)d_ws + 3197952);               //   147,456 B  (bf16 tiled W2)

    hipLaunchKernelGGL(pre_kernel,  dim3(519), dim3(256), 0, stream,
                       query, doc, sparse, W1, b1, W2, out_dense, out_sparse, Bws, Aq, W1cdf, W2t);
    hipLaunchKernelGGL(main_kernel, dim3(256), dim3(512), 0, stream,
                       Aq, Bws, W1cdf, W2t, b2, W3, b3, sparse, out_dense, out_final);
}

// Round 3
// 125.580 us; speedup vs baseline: 1.2330x; 1.0205x over previous
//
#include <hip/hip_runtime.h>
#include <hip/hip_bf16.h>

typedef __attribute__((ext_vector_type(2)))  float f32x2;
typedef __attribute__((ext_vector_type(4)))  float f32x4;
typedef __attribute__((ext_vector_type(16))) float f32x16;
typedef __attribute__((ext_vector_type(8)))  short bf16x8;
typedef __attribute__((ext_vector_type(2)))  unsigned int u32x2;
typedef __attribute__((ext_vector_type(4)))  unsigned int u32x4;

__device__ __forceinline__ short f2bf(float x){
    __hip_bfloat16 h = __float2bfloat16(x);
    return __builtin_bit_cast(short, h);
}
__device__ __forceinline__ float bf2f(short x){
    unsigned int u = ((unsigned int)(unsigned short)x) << 16;
    return __builtin_bit_cast(float, u);
}
// one packed RNE convert for a bf16 pair (hw v_cvt_pk_bf16_f32)
__device__ __forceinline__ unsigned int cvt2(float lo, float hi){
    unsigned int r;
    asm("v_cvt_pk_bf16_f32 %0, %1, %2" : "=v"(r) : "v"(lo), "v"(hi));
    return r;
}

// ---------------------------------------------------------------- pre0: all W1-independent prep
// blocks 0..255   : dense scores (16 docs x 32 q, f32x4 LDS inner loop) + sparse copy  [unchanged]
// blocks 256..327 : W1t bf16 tiling of W1a (rows 0..383) and W1b (rows 384..767) in the exact
//                   16x16x32 B-frag chunk order pre1 wants:
//                   chunk = half*288 + s*24 + ct; W1t[chunk*512 + lane*8 + j] =
//                   bf16(W1[(half*384 + s*32 + (lane>>4)*8 + j)*384 + ct*16 + (lane&15)])
// blocks 328..423 : docb = bf16(doc)  [4096x384, row-major]
// block  424      : qb16 = bf16(query) [32x384]
// block  425      : W1cdf f32 [768]: [0..383]=W1[768][:], [384..767]=W1[769][:]
// blocks 426..429 : W2t = W2 bf16 pre-tiled in main's 32x32-frag chunk order
__global__ __launch_bounds__(256)
void pre0_kernel(const float* __restrict__ query, const float* __restrict__ doc,
                 const float* __restrict__ sparse, const float* __restrict__ W1,
                 const float* __restrict__ W2,
                 float* __restrict__ out_dense, float* __restrict__ out_sparse,
                 short* __restrict__ W1t, short* __restrict__ docb, short* __restrict__ qb16,
                 float* __restrict__ W1cdf, short* __restrict__ W2t){
    __shared__ float ldsq[32*388];
    __shared__ float ldsd[16*388];
    const int b = blockIdx.x, tid = threadIdx.x;

    if (b < 256){
        const int d0 = b*16;
        #pragma unroll
        for (int i=0;i<12;i++){ int idx = tid + i*256; int row = idx/96, c4 = idx%96;
            *(f32x4*)(ldsq + row*388 + c4*4) = *(const f32x4*)(query + row*384 + c4*4); }
        #pragma unroll
        for (int i=0;i<6;i++){ int idx = tid + i*256; int row = idx/96, c4 = idx%96;
            *(f32x4*)(ldsd + row*388 + c4*4) = *(const f32x4*)(doc + (d0+row)*384 + c4*4); }
        __syncthreads();
        const int q = tid>>3, dg = tid&7;
        const f32x4* q4  = (const f32x4*)(ldsq + q*388);
        const f32x4* d4a = (const f32x4*)(ldsd + dg*388);
        const f32x4* d4b = (const f32x4*)(ldsd + (dg+8)*388);
        f32x4 s0 = {0.f,0.f,0.f,0.f}, s1 = {0.f,0.f,0.f,0.f};
        #pragma unroll 4
        for (int k=0;k<96;k++){
            const f32x4 qv = q4[k];
            s0 += qv*d4a[k];
            s1 += qv*d4b[k];
        }
        out_dense[q*4096 + d0 + dg]     = s0[0]+s0[1]+s0[2]+s0[3];
        out_dense[q*4096 + d0 + dg + 8] = s1[0]+s1[1]+s1[2]+s1[3];
        if (tid < 128){
            int qq = tid>>2, c4 = tid&3;
            *(f32x4*)(out_sparse + qq*4096 + d0 + c4*4) = *(const f32x4*)(sparse + qq*4096 + d0 + c4*4);
        }
    } else if (b < 328){
        // W1 tiling: 576 chunks x 64 lanes = 36864 lane-tasks; 72 blocks x 256 thr x 2 tasks
        const int lt0 = (b-256)*256 + tid;
        #pragma unroll
        for (int i=0;i<2;i++){
            const int lt    = lt0 + i*18432;
            const int chunk = lt >> 6, lane = lt & 63;
            const int cl = lane & 15, quad = lane >> 4;
            const int half = (chunk >= 288) ? 1 : 0;
            const int cs = chunk - half*288;
            const int s = cs/24, ct = cs%24;
            const float* src = W1 + (half*384 + s*32 + quad*8)*384 + ct*16 + cl;
            float v[8];
            #pragma unroll
            for (int j=0;j<8;j++) v[j] = src[j*384];
            u32x4 o;
            o[0] = cvt2(v[0],v[1]); o[1] = cvt2(v[2],v[3]);
            o[2] = cvt2(v[4],v[5]); o[3] = cvt2(v[6],v[7]);
            *(u32x4*)(W1t + chunk*512 + lane*8) = o;
        }
    } else if (b < 424){
        // docb: 393216 f32x4 chunks; 96 blocks x 256 thr x 16
        const int t0 = (b-328)*256 + tid;
        #pragma unroll
        for (int i=0;i<16;i++){
            const int g = t0 + i*24576;
            const f32x4 v = *(const f32x4*)(doc + g*4);
            u32x2 o; o[0] = cvt2(v[0],v[1]); o[1] = cvt2(v[2],v[3]);
            *(u32x2*)(docb + g*4) = o;
        }
    } else if (b == 424){
        // qb16: 3072 f32x4 chunks; 256 thr x 12
        #pragma unroll
        for (int i=0;i<12;i++){
            const int g = tid + i*256;
            const f32x4 v = *(const f32x4*)(query + g*4);
            u32x2 o; o[0] = cvt2(v[0],v[1]); o[1] = cvt2(v[2],v[3]);
            *(u32x2*)(qb16 + g*4) = o;
        }
    } else if (b == 425){
        #pragma unroll
        for (int i=0;i<3;i++){
            int o = tid + i*256;                     // < 768
            W1cdf[o] = (o < 384) ? W1[768*384 + o] : W1[769*384 + (o - 384)];
        }
    } else {
        // W2 bf16 tiling for 32x32x16 frags: chunk c=(s*6+t2)*64+lane_c, n=t2*32+(lane_c&31),
        // k=s*16+((lane_c>>5)&1)*8+j
        const int t0 = (b - 426)*256 + tid;
        #pragma unroll
        for (int i=0;i<9;i++){
            int c = t0 + i*1024;                     // < 9216
            int lane_c = c & 63, st = c >> 6;        // st < 144
            int s = st/6, t2 = st%6;
            int n = t2*32 + (lane_c&31), kb = s*16 + ((lane_c>>5)&1)*8;
            bf16x8 v;
            #pragma unroll
            for (int j=0;j<8;j++) v[j] = f2bf(W2[(kb+j)*192 + n]);
            *(bf16x8*)(W2t + c*8) = v;
        }
    }
}

// ---------------------------------------------------------------- pre1: Bws/Aq GEMM, all-vector
// blocks 0..255 : Bws(bf16)[16 doc rows] = docb @ W1b   (W1t half 1)
// blocks 256,257: Aq(f32)[16 q rows]     = qb16 @ W1a + b1 (W1t half 0)
// Per s-step per wave: 1 A-load (bf16x8) + 6 coalesced B-loads (bf16x8 from W1t) + 6 MFMA.
// Zero converts in the loop (inputs pre-converted by pre0); +1-step register prefetch.
__global__ __launch_bounds__(256)
void pre1_kernel(const short* __restrict__ docb, const short* __restrict__ qb16,
                 const short* __restrict__ W1t, const float* __restrict__ b1,
                 short* __restrict__ Bws, float* __restrict__ Aq){
    const int b = blockIdx.x, tid = threadIdx.x;
    const int w = tid >> 6, lane = tid & 63;
    const int cl = lane & 15, quad = lane >> 4;

    const short* src; const short* wt; int r0; bool isA;
    if (b < 256){ r0 = b*16;       src = docb; wt = W1t + 147456; isA = false; }
    else        { r0 = (b-256)*16; src = qb16; wt = W1t;          isA = true;  }

    const short* ap = src + (r0+cl)*384 + quad*8;
    const short* wp = wt + (w*6)*512 + lane*8;       // + s*12288 + tt*512

    f32x4 acc[6];
    #pragma unroll
    for (int t=0;t<6;t++) acc[t] = (f32x4){0.f,0.f,0.f,0.f};

    bf16x8 a_c = *(const bf16x8*)(ap);
    bf16x8 b_c[6];
    #pragma unroll
    for (int tt=0;tt<6;tt++) b_c[tt] = *(const bf16x8*)(wp + tt*512);

    #pragma unroll 1
    for (int s=0;s<12;s++){
        const int sn = (s < 11) ? s+1 : 0;           // dummy wrap on last iter
        const bf16x8 a_n = *(const bf16x8*)(ap + sn*32);
        bf16x8 b_n[6];
        #pragma unroll
        for (int tt=0;tt<6;tt++) b_n[tt] = *(const bf16x8*)(wp + sn*12288 + tt*512);
        #pragma unroll
        for (int tt=0;tt<6;tt++)
            acc[tt] = __builtin_amdgcn_mfma_f32_16x16x32_bf16(a_c, b_c[tt], acc[tt], 0, 0, 0);
        a_c = a_n;
        #pragma unroll
        for (int tt=0;tt<6;tt++) b_c[tt] = b_n[tt];
    }

    #pragma unroll
    for (int tt=0;tt<6;tt++){
        const int col = (w*6+tt)*16 + cl;
        if (isA){
            const float b1v = b1[col];
            #pragma unroll
            for (int r=0;r<4;r++)
                Aq[(r0 + quad*4 + r)*384 + col] = acc[tt][r] + b1v;
        } else {
            #pragma unroll
            for (int r=0;r<4;r++)
                Bws[(r0 + quad*4 + r)*384 + col] = f2bf(acc[tt][r]);
        }
    }
}

// ---------------------------------------------------------------- main fused MLP kernel (r2, unchanged)
// 256 blocks x 512 thr = 8 waves, 1 block/CU, one wave owns a doc column x all 32 q x all 192 n
// (6 x 32x32x16 tiles, acc = 96 AGPRs). Zero barriers after stage. W1c/W1d broadcast from LDS
// (lgkmcnt, off the vmcnt path); depth-3 prefetch of Bws/Aq; fr-build via v_cvt_pk_bf16_f32.
// A-frag: m=lane&31, k=(lane>>5)*8+j.  B-frag: n=lane&31, same k.
// C/D: col=lane&31, row=(reg&3)+8*(reg>>2)+4*(lane>>5)  [m74/m101-verified].
#define STEP(BW,A0,A1,S) do{                                                        \
    const int kf_ = (S)*16 + kbase;                                                 \
    const f32x4 wcA = *(const f32x4*)(lcd + kf_);                                   \
    const f32x4 wcB = *(const f32x4*)(lcd + kf_ + 4);                               \
    const f32x4 wdA = *(const f32x4*)(lcd + 384 + kf_);                             \
    const f32x4 wdB = *(const f32x4*)(lcd + 384 + kf_ + 4);                         \
    const short* lp_ = lw + ((S)*384 + lane)*8;                                     \
    const bf16x8 bfr0 = *(const bf16x8*)(lp_);                                      \
    const bf16x8 bfr1 = *(const bf16x8*)(lp_ + 512);                                \
    const bf16x8 bfr2 = *(const bf16x8*)(lp_ + 1024);                               \
    const bf16x8 bfr3 = *(const bf16x8*)(lp_ + 1536);                               \
    const bf16x8 bfr4 = *(const bf16x8*)(lp_ + 2048);                               \
    const bf16x8 bfr5 = *(const bf16x8*)(lp_ + 2560);                               \
    u32x4 frw_;                                                                     \
    { f32x2 h = {A0[0] + bf2f(BW[0]), A0[1] + bf2f(BW[1])};                         \
      h += dsv2 * (f32x2){wcA[0],wcA[1]}; h += ssv2 * (f32x2){wdA[0],wdA[1]};       \
      frw_[0] = cvt2(fmaxf(h[0],0.f), fmaxf(h[1],0.f)); }                           \
    { f32x2 h = {A0[2] + bf2f(BW[2]), A0[3] + bf2f(BW[3])};                         \
      h += dsv2 * (f32x2){wcA[2],wcA[3]}; h += ssv2 * (f32x2){wdA[2],wdA[3]};       \
      frw_[1] = cvt2(fmaxf(h[0],0.f), fmaxf(h[1],0.f)); }                           \
    { f32x2 h = {A1[0] + bf2f(BW[4]), A1[1] + bf2f(BW[5])};                         \
      h += dsv2 * (f32x2){wcB[0],wcB[1]}; h += ssv2 * (f32x2){wdB[0],wdB[1]};       \
      frw_[2] = cvt2(fmaxf(h[0],0.f), fmaxf(h[1],0.f)); }                           \
    { f32x2 h = {A1[2] + bf2f(BW[6]), A1[3] + bf2f(BW[7])};                         \
      h += dsv2 * (f32x2){wcB[2],wcB[3]}; h += ssv2 * (f32x2){wdB[2],wdB[3]};       \
      frw_[3] = cvt2(fmaxf(h[0],0.f), fmaxf(h[1],0.f)); }                           \
    const bf16x8 fr_ = __builtin_bit_cast(bf16x8, frw_);                            \
    acc[0] = __builtin_amdgcn_mfma_f32_32x32x16_bf16(fr_, bfr0, acc[0], 0, 0, 0);   \
    acc[1] = __builtin_amdgcn_mfma_f32_32x32x16_bf16(fr_, bfr1, acc[1], 0, 0, 0);   \
    acc[2] = __builtin_amdgcn_mfma_f32_32x32x16_bf16(fr_, bfr2, acc[2], 0, 0, 0);   \
    acc[3] = __builtin_amdgcn_mfma_f32_32x32x16_bf16(fr_, bfr3, acc[3], 0, 0, 0);   \
    acc[4] = __builtin_amdgcn_mfma_f32_32x32x16_bf16(fr_, bfr4, acc[4], 0, 0, 0);   \
    acc[5] = __builtin_amdgcn_mfma_f32_32x32x16_bf16(fr_, bfr5, acc[5], 0, 0, 0);   \
  }while(0)

__global__ __launch_bounds__(512, 2)
void main_kernel(const float* __restrict__ Aq, const short* __restrict__ Bws,
                 const float* __restrict__ W1cdf, const short* __restrict__ W2t,
                 const float* __restrict__ b2, const float* __restrict__ W3,
                 const float* __restrict__ b3, const float* __restrict__ sparse,
                 const float* __restrict__ dense_in, float* __restrict__ out_final){
    __shared__ __align__(16) short lw[73728];        // 147,456 B  W2 bf16 tiled
    __shared__ __align__(16) float lcd[768];         //   3,072 B  [0..383]=W1c, [384..767]=W1d
    const int tid = threadIdx.x;

    #pragma unroll
    for (int i=0;i<18;i++){
        int c = tid + i*512;
        *(f32x4*)(lw + c*8) = *(const f32x4*)(W2t + c*8);
    }
    if (tid < 192)
        *(f32x4*)(lcd + tid*4) = *(const f32x4*)(W1cdf + tid*4);
    __syncthreads();                                 // only barrier in the kernel

    const int lane = tid & 63, w = tid >> 6;
    const int m = lane & 31, q2 = lane >> 5;         // row m; k-half q2
    const int kbase = q2*8;
    const float b3v = b3[0];
    const int dcol0 = blockIdx.x*16 + w;

    // hoist per-column scalars for both t4 iterations
    const float dsv0 = dense_in[m*4096 + dcol0];
    const float ssv0 = sparse[m*4096 + dcol0];
    const float dsv1 = dense_in[m*4096 + dcol0 + 8];
    const float ssv1 = sparse[m*4096 + dcol0 + 8];

    #pragma unroll 1
    for (int t4=0; t4<2; t4++){
        const int dcol = dcol0 + t4*8;
        const float dsv = t4 ? dsv1 : dsv0;
        const float ssv = t4 ? ssv1 : ssv0;
        const f32x2 dsv2 = {dsv, dsv}, ssv2 = {ssv, ssv};

        f32x16 acc[6];
        #pragma unroll
        for (int t=0;t<6;t++)
            #pragma unroll
            for (int r=0;r<16;r++) acc[t][r] = 0.0f;

        const short* bp = Bws + dcol*384;
        const float* ap = Aq + m*384;

        // depth-3 prefetch: slots A(s), B(s+1), C(s+2)
        bf16x8 bwA = *(const bf16x8*)(bp + kbase);
        f32x4  aA0 = *(const f32x4*)(ap + kbase);
        f32x4  aA1 = *(const f32x4*)(ap + kbase + 4);
        bf16x8 bwB = *(const bf16x8*)(bp + 16 + kbase);
        f32x4  aB0 = *(const f32x4*)(ap + 16 + kbase);
        f32x4  aB1 = *(const f32x4*)(ap + 16 + kbase + 4);
        bf16x8 bwC = *(const bf16x8*)(bp + 32 + kbase);
        f32x4  aC0 = *(const f32x4*)(ap + 32 + kbase);
        f32x4  aC1 = *(const f32x4*)(ap + 32 + kbase + 4);

        #pragma unroll 1
        for (int s=0; s<24; s+=3){
            STEP(bwA, aA0, aA1, s);
            { const int kp = (s+3 < 24) ? (s+3)*16 + kbase : kbase;   // dummy wrap at tail
              bwA = *(const bf16x8*)(bp + kp);
              aA0 = *(const f32x4*)(ap + kp);
              aA1 = *(const f32x4*)(ap + kp + 4); }
            STEP(bwB, aB0, aB1, s+1);
            { const int kp = (s+4 < 24) ? (s+4)*16 + kbase : kbase;
              bwB = *(const bf16x8*)(bp + kp);
              aB0 = *(const f32x4*)(ap + kp);
              aB1 = *(const f32x4*)(ap + kp + 4); }
            STEP(bwC, aC0, aC1, s+2);
            { const int kp = (s+5 < 24) ? (s+5)*16 + kbase : kbase;
              bwC = *(const bf16x8*)(bp + kp);
              aC0 = *(const f32x4*)(ap + kp);
              aC1 = *(const f32x4*)(ap + kp + 4); }
        }

        // layer 3: p[r] = sum_n relu(h2[row_r][n]+b2[n])*W3[n]; this lane covers n = t*32+m
        float p[16];
        #pragma unroll
        for (int r=0;r<16;r++) p[r] = 0.0f;
        #pragma unroll
        for (int t=0;t<6;t++){
            const int n = t*32 + m;
            const float b2v = b2[n];
            const float w3v = W3[n];
            #pragma unroll
            for (int r=0;r<16;r++)
                p[r] += fmaxf(acc[t][r] + b2v, 0.0f) * w3v;
        }
        // reduce over the 32 lanes of this q2 half (masks 1..16 stay within the half)
        #pragma unroll
        for (int mask=1; mask<32; mask<<=1){
            #pragma unroll
            for (int r=0;r<16;r++) p[r] += __shfl_xor(p[r], mask);
        }
        // lane m<16 takes p[m] (static cndmask chain; no dynamic reg indexing)
        float myp = p[0];
        #pragma unroll
        for (int r=1;r<16;r++) myp = (m==r) ? p[r] : myp;
        if (m < 16){
            const int row = (m&3) + 8*(m>>2) + 4*q2;
            float logit = myp + b3v;
            float wgt = 1.0f/(1.0f + __expf(-logit));
            float dd = dense_in[row*4096 + dcol];
            float ss = sparse[row*4096 + dcol];
            out_final[row*4096 + dcol] = wgt*dd + (1.0f - wgt)*ss;
        }
    }
}

// ---------------------------------------------------------------- launch
extern "C" void kernel_launch(void* const* d_in, const int* in_sizes, int n_in,
                              void* d_out, int out_size, void* d_ws, size_t ws_size,
                              hipStream_t stream){
    const float* query  = (const float*)d_in[0];
    const float* doc    = (const float*)d_in[1];
    const float* sparse = (const float*)d_in[2];
    const float* W1     = (const float*)d_in[3];
    const float* b1     = (const float*)d_in[4];
    const float* W2     = (const float*)d_in[5];
    const float* b2     = (const float*)d_in[6];
    const float* W3     = (const float*)d_in[7];
    const float* b3     = (const float*)d_in[8];

    float* out_final  = (float*)d_out;                 // [32,4096]
    float* out_dense  = (float*)d_out + 131072;        // [32,4096]
    float* out_sparse = (float*)d_out + 262144;        // [32,4096]

    // workspace layout (16B-aligned), total 7,105,536 B
    short* Bws   = (short*)d_ws;                                  // 3,145,728 B  (bf16 [4096][384])
    float* Aq    = (float*)((char*)d_ws + 3145728);               //    49,152 B  (f32  [32][384])
    float* W1cdf = (float*)((char*)d_ws + 3194880);               //     3,072 B  (f32  [768])
    short* W2t   = (short*)((char*)d_ws + 3197952);               //   147,456 B  (bf16 tiled W2)
    short* W1t   = (short*)((char*)d_ws + 3345408);               //   589,824 B  (bf16 tiled W1a+W1b)
    short* docb  = (short*)((char*)d_ws + 3935232);               // 3,145,728 B  (bf16 [4096][384])
    short* qb16  = (short*)((char*)d_ws + 7080960);               //    24,576 B  (bf16 [32][384])

    hipLaunchKernelGGL(pre0_kernel, dim3(430), dim3(256), 0, stream,
                       query, doc, sparse, W1, W2, out_dense, out_sparse,
                       W1t, docb, qb16, W1cdf, W2t);
    hipLaunchKernelGGL(pre1_kernel, dim3(258), dim3(256), 0, stream,
                       docb, qb16, W1t, b1, Bws, Aq);
    hipLaunchKernelGGL(main_kernel, dim3(256), dim3(512), 0, stream,
                       Aq, Bws, W1cdf, W2t, b2, W3, b3, sparse, out_dense, out_final);
}

// Round 4
// 125.276 us; speedup vs baseline: 1.2360x; 1.0024x over previous
//
#include <hip/hip_runtime.h>
#include <hip/hip_bf16.h>

typedef __attribute__((ext_vector_type(2)))  float f32x2;
typedef __attribute__((ext_vector_type(4)))  float f32x4;
typedef __attribute__((ext_vector_type(16))) float f32x16;
typedef __attribute__((ext_vector_type(8)))  short bf16x8;
typedef __attribute__((ext_vector_type(2)))  unsigned int u32x2;
typedef __attribute__((ext_vector_type(4)))  unsigned int u32x4;

__device__ __forceinline__ short f2bf(float x){
    __hip_bfloat16 h = __float2bfloat16(x);
    return __builtin_bit_cast(short, h);
}
__device__ __forceinline__ float bf2f(short x){
    unsigned int u = ((unsigned int)(unsigned short)x) << 16;
    return __builtin_bit_cast(float, u);
}
// one packed RNE convert for a bf16 pair (hw v_cvt_pk_bf16_f32)
__device__ __forceinline__ unsigned int cvt2(float lo, float hi){
    unsigned int r;
    asm("v_cvt_pk_bf16_f32 %0, %1, %2" : "=v"(r) : "v"(lo), "v"(hi));
    return r;
}

// ---------------------------------------------------------------- pre0: all W1-independent prep
// blocks 0..255   : dense scores (16 docs x 32 q, f32x4 LDS inner loop) + sparse copy
// blocks 256..327 : W1t bf16 tiling of W1a/W1b in 16x16x32 B-frag chunk order (for pre1)
// blocks 328..423 : docb = bf16(doc)  [4096x384]
// block  424      : qb16 = bf16(query) [32x384]
// block  425      : W1cdf f32 [768]: [0..383]=W1[768][:], [384..767]=W1[769][:]
// blocks 426..429 : W2t = W2 bf16 pre-tiled in 16x16x32 B-frag chunk order for main:
//                   chunk c = (s*12 + t)*64 + lane; W2t[c*8+j] = bf16(W2[k][n]),
//                   k = s*32 + ((lane>>4)&3)*8 + j,  n = t*16 + (lane&15)   (s<12, t<12)
__global__ __launch_bounds__(256)
void pre0_kernel(const float* __restrict__ query, const float* __restrict__ doc,
                 const float* __restrict__ sparse, const float* __restrict__ W1,
                 const float* __restrict__ W2,
                 float* __restrict__ out_dense, float* __restrict__ out_sparse,
                 short* __restrict__ W1t, short* __restrict__ docb, short* __restrict__ qb16,
                 float* __restrict__ W1cdf, short* __restrict__ W2t){
    __shared__ float ldsq[32*388];
    __shared__ float ldsd[16*388];
    const int b = blockIdx.x, tid = threadIdx.x;

    if (b < 256){
        const int d0 = b*16;
        #pragma unroll
        for (int i=0;i<12;i++){ int idx = tid + i*256; int row = idx/96, c4 = idx%96;
            *(f32x4*)(ldsq + row*388 + c4*4) = *(const f32x4*)(query + row*384 + c4*4); }
        #pragma unroll
        for (int i=0;i<6;i++){ int idx = tid + i*256; int row = idx/96, c4 = idx%96;
            *(f32x4*)(ldsd + row*388 + c4*4) = *(const f32x4*)(doc + (d0+row)*384 + c4*4); }
        __syncthreads();
        const int q = tid>>3, dg = tid&7;
        const f32x4* q4  = (const f32x4*)(ldsq + q*388);
        const f32x4* d4a = (const f32x4*)(ldsd + dg*388);
        const f32x4* d4b = (const f32x4*)(ldsd + (dg+8)*388);
        f32x4 s0 = {0.f,0.f,0.f,0.f}, s1 = {0.f,0.f,0.f,0.f};
        #pragma unroll 4
        for (int k=0;k<96;k++){
            const f32x4 qv = q4[k];
            s0 += qv*d4a[k];
            s1 += qv*d4b[k];
        }
        out_dense[q*4096 + d0 + dg]     = s0[0]+s0[1]+s0[2]+s0[3];
        out_dense[q*4096 + d0 + dg + 8] = s1[0]+s1[1]+s1[2]+s1[3];
        if (tid < 128){
            int qq = tid>>2, c4 = tid&3;
            *(f32x4*)(out_sparse + qq*4096 + d0 + c4*4) = *(const f32x4*)(sparse + qq*4096 + d0 + c4*4);
        }
    } else if (b < 328){
        // W1 tiling: 576 chunks x 64 lanes = 36864 lane-tasks; 72 blocks x 256 thr x 2 tasks
        const int lt0 = (b-256)*256 + tid;
        #pragma unroll
        for (int i=0;i<2;i++){
            const int lt    = lt0 + i*18432;
            const int chunk = lt >> 6, lane = lt & 63;
            const int cl = lane & 15, quad = lane >> 4;
            const int half = (chunk >= 288) ? 1 : 0;
            const int cs = chunk - half*288;
            const int s = cs/24, ct = cs%24;
            const float* src = W1 + (half*384 + s*32 + quad*8)*384 + ct*16 + cl;
            float v[8];
            #pragma unroll
            for (int j=0;j<8;j++) v[j] = src[j*384];
            u32x4 o;
            o[0] = cvt2(v[0],v[1]); o[1] = cvt2(v[2],v[3]);
            o[2] = cvt2(v[4],v[5]); o[3] = cvt2(v[6],v[7]);
            *(u32x4*)(W1t + chunk*512 + lane*8) = o;
        }
    } else if (b < 424){
        // docb: 393216 f32x4 chunks; 96 blocks x 256 thr x 16
        const int t0 = (b-328)*256 + tid;
        #pragma unroll
        for (int i=0;i<16;i++){
            const int g = t0 + i*24576;
            const f32x4 v = *(const f32x4*)(doc + g*4);
            u32x2 o; o[0] = cvt2(v[0],v[1]); o[1] = cvt2(v[2],v[3]);
            *(u32x2*)(docb + g*4) = o;
        }
    } else if (b == 424){
        // qb16: 3072 f32x4 chunks; 256 thr x 12
        #pragma unroll
        for (int i=0;i<12;i++){
            const int g = tid + i*256;
            const f32x4 v = *(const f32x4*)(query + g*4);
            u32x2 o; o[0] = cvt2(v[0],v[1]); o[1] = cvt2(v[2],v[3]);
            *(u32x2*)(qb16 + g*4) = o;
        }
    } else if (b == 425){
        #pragma unroll
        for (int i=0;i<3;i++){
            int o = tid + i*256;                     // < 768
            W1cdf[o] = (o < 384) ? W1[768*384 + o] : W1[769*384 + (o - 384)];
        }
    } else {
        // W2 bf16 tiling for main's 16x16x32 B-frags (see header comment)
        const int t0 = (b - 426)*256 + tid;
        #pragma unroll
        for (int i=0;i<9;i++){
            int c = t0 + i*1024;                     // < 9216
            int lane_c = c & 63, st = c >> 6;        // st < 144
            int s = st/12, t2 = st%12;
            int n = t2*16 + (lane_c&15), kb = s*32 + ((lane_c>>4)&3)*8;
            bf16x8 v;
            #pragma unroll
            for (int j=0;j<8;j++) v[j] = f2bf(W2[(kb+j)*192 + n]);
            *(bf16x8*)(W2t + c*8) = v;
        }
    }
}

// ---------------------------------------------------------------- pre1: Bws/Aq GEMM (unchanged)
__global__ __launch_bounds__(256)
void pre1_kernel(const short* __restrict__ docb, const short* __restrict__ qb16,
                 const short* __restrict__ W1t, const float* __restrict__ b1,
                 short* __restrict__ Bws, float* __restrict__ Aq){
    const int b = blockIdx.x, tid = threadIdx.x;
    const int w = tid >> 6, lane = tid & 63;
    const int cl = lane & 15, quad = lane >> 4;

    const short* src; const short* wt; int r0; bool isA;
    if (b < 256){ r0 = b*16;       src = docb; wt = W1t + 147456; isA = false; }
    else        { r0 = (b-256)*16; src = qb16; wt = W1t;          isA = true;  }

    const short* ap = src + (r0+cl)*384 + quad*8;
    const short* wp = wt + (w*6)*512 + lane*8;       // + s*12288 + tt*512

    f32x4 acc[6];
    #pragma unroll
    for (int t=0;t<6;t++) acc[t] = (f32x4){0.f,0.f,0.f,0.f};

    bf16x8 a_c = *(const bf16x8*)(ap);
    bf16x8 b_c[6];
    #pragma unroll
    for (int tt=0;tt<6;tt++) b_c[tt] = *(const bf16x8*)(wp + tt*512);

    #pragma unroll 1
    for (int s=0;s<12;s++){
        const int sn = (s < 11) ? s+1 : 0;           // dummy wrap on last iter
        const bf16x8 a_n = *(const bf16x8*)(ap + sn*32);
        bf16x8 b_n[6];
        #pragma unroll
        for (int tt=0;tt<6;tt++) b_n[tt] = *(const bf16x8*)(wp + sn*12288 + tt*512);
        #pragma unroll
        for (int tt=0;tt<6;tt++)
            acc[tt] = __builtin_amdgcn_mfma_f32_16x16x32_bf16(a_c, b_c[tt], acc[tt], 0, 0, 0);
        a_c = a_n;
        #pragma unroll
        for (int tt=0;tt<6;tt++) b_c[tt] = b_n[tt];
    }

    #pragma unroll
    for (int tt=0;tt<6;tt++){
        const int col = (w*6+tt)*16 + cl;
        if (isA){
            const float b1v = b1[col];
            #pragma unroll
            for (int r=0;r<4;r++)
                Aq[(r0 + quad*4 + r)*384 + col] = acc[tt][r] + b1v;
        } else {
            #pragma unroll
            for (int r=0;r<4;r++)
                Bws[(r0 + quad*4 + r)*384 + col] = f2bf(acc[tt][r]);
        }
    }
}

// ---------------------------------------------------------------- main fused MLP kernel — m-split
// 256 blocks x 1024 thr = 16 waves/CU = 4 waves/SIMD (acc drops 96->48 via 16x16x32 MFMA; total
// regs <=128 enforced by launch bounds). Wave w: column slot w>>1, m-half w&1 -> each wave owns
// 16 COMPLETE q-rows of one doc column: fr-build is PARTITIONED (not duplicated, round-1 bug)
// and no cross-wave combine is needed in the epilogue. 16 cols/block (t4 in {0,1}).
// Cost accepted: both m-halves read full W2 from LDS (2x LDS traffic, ~15us/CU floor) in
// exchange for 2x latency-hiding occupancy (round-3 diagnosis: 25% overlap efficiency).
// A-frag: m=lane&15, k=(lane>>4)*8+j.  B-frag: n=lane&15, same k.
// C/D: col=lane&15, row=(lane>>4)*4+reg  [m89/m91-verified].
__global__ __launch_bounds__(1024)
void main_kernel(const float* __restrict__ Aq, const short* __restrict__ Bws,
                 const float* __restrict__ W1cdf, const short* __restrict__ W2t,
                 const float* __restrict__ b2, const float* __restrict__ W3,
                 const float* __restrict__ b3, const float* __restrict__ sparse,
                 const float* __restrict__ dense_in, float* __restrict__ out_final){
    __shared__ __align__(16) short lw[73728];        // 147,456 B  W2 bf16 (16x16x32 frag order)
    __shared__ __align__(16) float lcd[768];         //   3,072 B  [0..383]=W1c, [384..767]=W1d
    const int tid = threadIdx.x;

    #pragma unroll
    for (int i=0;i<9;i++){
        int c = tid + i*1024;                        // < 9216
        *(f32x4*)(lw + c*8) = *(const f32x4*)(W2t + c*8);
    }
    if (tid < 192)
        *(f32x4*)(lcd + tid*4) = *(const f32x4*)(W1cdf + tid*4);
    __syncthreads();                                 // only barrier in the kernel

    const int lane = tid & 63, w = tid >> 6;
    const int colslot = w >> 1, mhalf = w & 1;
    const int cl = lane & 15, g = lane >> 4;
    const int mrow = mhalf*16 + cl;                  // q-row of this lane's A-frag
    const int k8 = g*8;                              // k-offset within a K=32 step
    const float b3v = b3[0];
    const int dcol0 = blockIdx.x*16 + colslot;

    #pragma unroll 1
    for (int t4=0; t4<2; t4++){
        const int dcol = dcol0 + t4*8;
        const float dsv = dense_in[mrow*4096 + dcol];
        const float ssv = sparse[mrow*4096 + dcol];
        const f32x2 dsv2 = {dsv, dsv}, ssv2 = {ssv, ssv};

        f32x4 acc[12];
        #pragma unroll
        for (int t=0;t<12;t++) acc[t] = (f32x4){0.f,0.f,0.f,0.f};

        const short* bp = Bws + dcol*384;
        const float* ap = Aq + mrow*384;

        // depth-2 prefetch (slot C = current step)
        bf16x8 bwC = *(const bf16x8*)(bp + k8);
        f32x4  aC0 = *(const f32x4*)(ap + k8);
        f32x4  aC1 = *(const f32x4*)(ap + k8 + 4);

        #pragma unroll 1
        for (int s=0; s<12; s++){
            const int kn = (s < 11) ? (s+1)*32 + k8 : k8;    // dummy wrap at tail
            const bf16x8 bwN = *(const bf16x8*)(bp + kn);
            const f32x4  aN0 = *(const f32x4*)(ap + kn);
            const f32x4  aN1 = *(const f32x4*)(ap + kn + 4);

            const int kf = s*32 + k8;
            const f32x4 wcA = *(const f32x4*)(lcd + kf);
            const f32x4 wcB = *(const f32x4*)(lcd + kf + 4);
            const f32x4 wdA = *(const f32x4*)(lcd + 384 + kf);
            const f32x4 wdB = *(const f32x4*)(lcd + 384 + kf + 4);

            u32x4 frw;
            { f32x2 h = {aC0[0] + bf2f(bwC[0]), aC0[1] + bf2f(bwC[1])};
              h += dsv2 * (f32x2){wcA[0],wcA[1]}; h += ssv2 * (f32x2){wdA[0],wdA[1]};
              frw[0] = cvt2(fmaxf(h[0],0.f), fmaxf(h[1],0.f)); }
            { f32x2 h = {aC0[2] + bf2f(bwC[2]), aC0[3] + bf2f(bwC[3])};
              h += dsv2 * (f32x2){wcA[2],wcA[3]}; h += ssv2 * (f32x2){wdA[2],wdA[3]};
              frw[1] = cvt2(fmaxf(h[0],0.f), fmaxf(h[1],0.f)); }
            { f32x2 h = {aC1[0] + bf2f(bwC[4]), aC1[1] + bf2f(bwC[5])};
              h += dsv2 * (f32x2){wcB[0],wcB[1]}; h += ssv2 * (f32x2){wdB[0],wdB[1]};
              frw[2] = cvt2(fmaxf(h[0],0.f), fmaxf(h[1],0.f)); }
            { f32x2 h = {aC1[2] + bf2f(bwC[6]), aC1[3] + bf2f(bwC[7])};
              h += dsv2 * (f32x2){wcB[2],wcB[3]}; h += ssv2 * (f32x2){wdB[2],wdB[3]};
              frw[3] = cvt2(fmaxf(h[0],0.f), fmaxf(h[1],0.f)); }
            const bf16x8 fr = __builtin_bit_cast(bf16x8, frw);

            // 12 n-tiles in groups of 3 (limits live bfr regs to 12)
            const short* lp = lw + s*6144 + lane*8;          // s*12*512 shorts
            #pragma unroll
            for (int tg=0; tg<4; tg++){
                const bf16x8 f0 = *(const bf16x8*)(lp + (tg*3+0)*512);
                const bf16x8 f1 = *(const bf16x8*)(lp + (tg*3+1)*512);
                const bf16x8 f2 = *(const bf16x8*)(lp + (tg*3+2)*512);
                acc[tg*3+0] = __builtin_amdgcn_mfma_f32_16x16x32_bf16(fr, f0, acc[tg*3+0], 0, 0, 0);
                acc[tg*3+1] = __builtin_amdgcn_mfma_f32_16x16x32_bf16(fr, f1, acc[tg*3+1], 0, 0, 0);
                acc[tg*3+2] = __builtin_amdgcn_mfma_f32_16x16x32_bf16(fr, f2, acc[tg*3+2], 0, 0, 0);
            }
            bwC = bwN; aC0 = aN0; aC1 = aN1;
        }

        // layer 3: this lane covers n = t*16+cl for rows g*4+r (+mhalf*16)
        float p0=0.f, p1=0.f, p2=0.f, p3=0.f;
        #pragma unroll
        for (int t=0;t<12;t++){
            const int n = t*16 + cl;
            const float b2v = b2[n];
            const float w3v = W3[n];
            p0 += fmaxf(acc[t][0] + b2v, 0.0f) * w3v;
            p1 += fmaxf(acc[t][1] + b2v, 0.0f) * w3v;
            p2 += fmaxf(acc[t][2] + b2v, 0.0f) * w3v;
            p3 += fmaxf(acc[t][3] + b2v, 0.0f) * w3v;
        }
        // reduce over the 16 lanes of this g-group (masks 1..8 stay within the group)
        #pragma unroll
        for (int mask=1; mask<16; mask<<=1){
            p0 += __shfl_xor(p0, mask);
            p1 += __shfl_xor(p1, mask);
            p2 += __shfl_xor(p2, mask);
            p3 += __shfl_xor(p3, mask);
        }
        // lane cl<4 writes row mhalf*16 + g*4 + cl (static cndmask chain)
        float myp = p0;
        myp = (cl==1) ? p1 : myp;
        myp = (cl==2) ? p2 : myp;
        myp = (cl==3) ? p3 : myp;
        if (cl < 4){
            const int row = mhalf*16 + g*4 + cl;
            const float logit = myp + b3v;
            const float wgt = 1.0f/(1.0f + __expf(-logit));
            const float dd = dense_in[row*4096 + dcol];
            const float ss = sparse[row*4096 + dcol];
            out_final[row*4096 + dcol] = wgt*dd + (1.0f - wgt)*ss;
        }
    }
}

// ---------------------------------------------------------------- launch
extern "C" void kernel_launch(void* const* d_in, const int* in_sizes, int n_in,
                              void* d_out, int out_size, void* d_ws, size_t ws_size,
                              hipStream_t stream){
    const float* query  = (const float*)d_in[0];
    const float* doc    = (const float*)d_in[1];
    const float* sparse = (const float*)d_in[2];
    const float* W1     = (const float*)d_in[3];
    const float* b1     = (const float*)d_in[4];
    const float* W2     = (const float*)d_in[5];
    const float* b2     = (const float*)d_in[6];
    const float* W3     = (const float*)d_in[7];
    const float* b3     = (const float*)d_in[8];

    float* out_final  = (float*)d_out;                 // [32,4096]
    float* out_dense  = (float*)d_out + 131072;        // [32,4096]
    float* out_sparse = (float*)d_out + 262144;        // [32,4096]

    // workspace layout (16B-aligned), total 7,105,536 B
    short* Bws   = (short*)d_ws;                                  // 3,145,728 B  (bf16 [4096][384])
    float* Aq    = (float*)((char*)d_ws + 3145728);               //    49,152 B  (f32  [32][384])
    float* W1cdf = (float*)((char*)d_ws + 3194880);               //     3,072 B  (f32  [768])
    short* W2t   = (short*)((char*)d_ws + 3197952);               //   147,456 B  (bf16 tiled W2)
    short* W1t   = (short*)((char*)d_ws + 3345408);               //   589,824 B  (bf16 tiled W1a+W1b)
    short* docb  = (short*)((char*)d_ws + 3935232);               // 3,145,728 B  (bf16 [4096][384])
    short* qb16  = (short*)((char*)d_ws + 7080960);               //    24,576 B  (bf16 [32][384])

    hipLaunchKernelGGL(pre0_kernel, dim3(430), dim3(256), 0, stream,
                       query, doc, sparse, W1, W2, out_dense, out_sparse,
                       W1t, docb, qb16, W1cdf, W2t);
    hipLaunchKernelGGL(pre1_kernel, dim3(258), dim3(256), 0, stream,
                       docb, qb16, W1t, b1, Bws, Aq);
    hipLaunchKernelGGL(main_kernel, dim3(256), dim3(1024), 0, stream,
                       Aq, Bws, W1cdf, W2t, b2, W3, b3, sparse, out_dense, out_final);
}

// Round 5
// 123.372 us; speedup vs baseline: 1.2551x; 1.0154x over previous
//
#include <hip/hip_runtime.h>
#include <hip/hip_bf16.h>

typedef __attribute__((ext_vector_type(2)))  float f32x2;
typedef __attribute__((ext_vector_type(4)))  float f32x4;
typedef __attribute__((ext_vector_type(8)))  short bf16x8;
typedef __attribute__((ext_vector_type(2)))  unsigned int u32x2;
typedef __attribute__((ext_vector_type(4)))  unsigned int u32x4;

__device__ __forceinline__ short f2bf(float x){
    __hip_bfloat16 h = __float2bfloat16(x);
    return __builtin_bit_cast(short, h);
}
__device__ __forceinline__ float bf2f(short x){
    unsigned int u = ((unsigned int)(unsigned short)x) << 16;
    return __builtin_bit_cast(float, u);
}
// one packed RNE convert for a bf16 pair (hw v_cvt_pk_bf16_f32)
__device__ __forceinline__ unsigned int cvt2(float lo, float hi){
    unsigned int r;
    asm("v_cvt_pk_bf16_f32 %0, %1, %2" : "=v"(r) : "v"(lo), "v"(hi));
    return r;
}

// ---------------------------------------------------------------- pre0: pure conversion/tiling prep
// (dense-score blocks REMOVED -> now MFMA-fused into pre1; round-4 diagnosis: they were ~25-30us
//  of LDS-latency-bound time at 12.5% occupancy)
// blocks 0..71    : W1t bf16 tiling of W1a/W1b in 16x16x32 B-frag chunk order (for pre1)
// blocks 72..167  : docb = bf16(doc)  [4096x384]
// block  168      : qb16 = bf16(query) [32x384]
// block  169      : W1cdf f32 [768]: [0..383]=W1[768][:], [384..767]=W1[769][:]
// blocks 170..173 : W2t = W2 bf16 pre-tiled in 16x16x32 B-frag chunk order for main:
//                   chunk c = (s*12 + t)*64 + lane; W2t[c*8+j] = bf16(W2[k][n]),
//                   k = s*32 + ((lane>>4)&3)*8 + j,  n = t*16 + (lane&15)   (s<12, t<12)
__global__ __launch_bounds__(256)
void pre0_kernel(const float* __restrict__ query, const float* __restrict__ doc,
                 const float* __restrict__ W1, const float* __restrict__ W2,
                 short* __restrict__ W1t, short* __restrict__ docb, short* __restrict__ qb16,
                 float* __restrict__ W1cdf, short* __restrict__ W2t){
    const int b = blockIdx.x, tid = threadIdx.x;

    if (b < 72){
        // W1 tiling: 576 chunks x 64 lanes = 36864 lane-tasks; 72 blocks x 256 thr x 2 tasks
        const int lt0 = b*256 + tid;
        #pragma unroll
        for (int i=0;i<2;i++){
            const int lt    = lt0 + i*18432;
            const int chunk = lt >> 6, lane = lt & 63;
            const int cl = lane & 15, quad = lane >> 4;
            const int half = (chunk >= 288) ? 1 : 0;
            const int cs = chunk - half*288;
            const int s = cs/24, ct = cs%24;
            const float* src = W1 + (half*384 + s*32 + quad*8)*384 + ct*16 + cl;
            float v[8];
            #pragma unroll
            for (int j=0;j<8;j++) v[j] = src[j*384];
            u32x4 o;
            o[0] = cvt2(v[0],v[1]); o[1] = cvt2(v[2],v[3]);
            o[2] = cvt2(v[4],v[5]); o[3] = cvt2(v[6],v[7]);
            *(u32x4*)(W1t + chunk*512 + lane*8) = o;
        }
    } else if (b < 168){
        // docb: 393216 f32x4 chunks; 96 blocks x 256 thr x 16
        const int t0 = (b-72)*256 + tid;
        #pragma unroll
        for (int i=0;i<16;i++){
            const int g = t0 + i*24576;
            const f32x4 v = *(const f32x4*)(doc + g*4);
            u32x2 o; o[0] = cvt2(v[0],v[1]); o[1] = cvt2(v[2],v[3]);
            *(u32x2*)(docb + g*4) = o;
        }
    } else if (b == 168){
        // qb16: 3072 f32x4 chunks; 256 thr x 12
        #pragma unroll
        for (int i=0;i<12;i++){
            const int g = tid + i*256;
            const f32x4 v = *(const f32x4*)(query + g*4);
            u32x2 o; o[0] = cvt2(v[0],v[1]); o[1] = cvt2(v[2],v[3]);
            *(u32x2*)(qb16 + g*4) = o;
        }
    } else if (b == 169){
        #pragma unroll
        for (int i=0;i<3;i++){
            int o = tid + i*256;                     // < 768
            W1cdf[o] = (o < 384) ? W1[768*384 + o] : W1[769*384 + (o - 384)];
        }
    } else {
        // W2 bf16 tiling for main's 16x16x32 B-frags (see header comment)
        const int t0 = (b - 170)*256 + tid;
        #pragma unroll
        for (int i=0;i<9;i++){
            int c = t0 + i*1024;                     // < 9216
            int lane_c = c & 63, st = c >> 6;        // st < 144
            int s = st/12, t2 = st%12;
            int n = t2*16 + (lane_c&15), kb = s*32 + ((lane_c>>4)&3)*8;
            bf16x8 v;
            #pragma unroll
            for (int j=0;j<8;j++) v[j] = f2bf(W2[(kb+j)*192 + n]);
            *(bf16x8*)(W2t + c*8) = v;
        }
    }
}

// ---------------------------------------------------------------- pre1: Bws/Aq GEMM + FUSED dense
// blocks 0..255 : Bws(bf16)[16 doc rows] = docb @ W1b  AND  dense[32 q, these 16 docs] =
//                 docb-rows @ qb16^T (one extra 16x16x32 MFMA/step; A-frags are ALREADY loaded
//                 for the Bws GEMM, so dense is nearly free). Also copies the sparse slice.
// blocks 256,257: Aq(f32)[16 q rows] = qb16 @ W1a + b1
// All waves compute the dense MFMA (uniform 7 MFMA/step, no divergence); only waves 0,1 of
// doc-blocks store it (q-tile = w&1). Dense via bf16 inputs: |err| ~ 5e-4 << 0.0039 absmax.
__global__ __launch_bounds__(256)
void pre1_kernel(const short* __restrict__ docb, const short* __restrict__ qb16,
                 const short* __restrict__ W1t, const float* __restrict__ b1,
                 const float* __restrict__ sparse,
                 short* __restrict__ Bws, float* __restrict__ Aq,
                 float* __restrict__ out_dense, float* __restrict__ out_sparse){
    const int b = blockIdx.x, tid = threadIdx.x;
    const int w = tid >> 6, lane = tid & 63;
    const int cl = lane & 15, quad = lane >> 4;

    const short* src; const short* wt; int r0; bool isA;
    if (b < 256){ r0 = b*16;       src = docb; wt = W1t + 147456; isA = false; }
    else        { r0 = (b-256)*16; src = qb16; wt = W1t;          isA = true;  }

    const int tq = w & 1;                            // dense q-tile this wave covers
    const short* ap = src + (r0+cl)*384 + quad*8;
    const short* wp = wt + (w*6)*512 + lane*8;       // + s*12288 + tt*512
    const short* qp = qb16 + (tq*16 + cl)*384 + quad*8;

    f32x4 acc[6];
    #pragma unroll
    for (int t=0;t<6;t++) acc[t] = (f32x4){0.f,0.f,0.f,0.f};
    f32x4 accd = (f32x4){0.f,0.f,0.f,0.f};

    bf16x8 a_c = *(const bf16x8*)(ap);
    bf16x8 qd_c = *(const bf16x8*)(qp);
    bf16x8 b_c[6];
    #pragma unroll
    for (int tt=0;tt<6;tt++) b_c[tt] = *(const bf16x8*)(wp + tt*512);

    #pragma unroll 1
    for (int s=0;s<12;s++){
        const int sn = (s < 11) ? s+1 : 0;           // dummy wrap on last iter
        const bf16x8 a_n  = *(const bf16x8*)(ap + sn*32);
        const bf16x8 qd_n = *(const bf16x8*)(qp + sn*32);
        bf16x8 b_n[6];
        #pragma unroll
        for (int tt=0;tt<6;tt++) b_n[tt] = *(const bf16x8*)(wp + sn*12288 + tt*512);
        #pragma unroll
        for (int tt=0;tt<6;tt++)
            acc[tt] = __builtin_amdgcn_mfma_f32_16x16x32_bf16(a_c, b_c[tt], acc[tt], 0, 0, 0);
        accd = __builtin_amdgcn_mfma_f32_16x16x32_bf16(a_c, qd_c, accd, 0, 0, 0);
        a_c = a_n; qd_c = qd_n;
        #pragma unroll
        for (int tt=0;tt<6;tt++) b_c[tt] = b_n[tt];
    }

    #pragma unroll
    for (int tt=0;tt<6;tt++){
        const int col = (w*6+tt)*16 + cl;
        if (isA){
            const float b1v = b1[col];
            #pragma unroll
            for (int r=0;r<4;r++)
                Aq[(r0 + quad*4 + r)*384 + col] = acc[tt][r] + b1v;
        } else {
            #pragma unroll
            for (int r=0;r<4;r++)
                Bws[(r0 + quad*4 + r)*384 + col] = f2bf(acc[tt][r]);
        }
    }
    if (!isA){
        // dense store: C/D 16x16 layout col=lane&15 -> q within tile, row=quad*4+r -> doc
        if (w < 2){
            #pragma unroll
            for (int r=0;r<4;r++)
                out_dense[(tq*16 + cl)*4096 + r0 + quad*4 + r] = accd[r];
        }
        // sparse slice copy: 32 q x 16 docs as f32x4
        if (tid < 128){
            const int qq = tid>>2, c4 = tid&3;
            *(f32x4*)(out_sparse + qq*4096 + r0 + c4*4) =
                *(const f32x4*)(sparse + qq*4096 + r0 + c4*4);
        }
    }
}

// ---------------------------------------------------------------- main fused MLP kernel — m-split (r4, unchanged)
// 256 blocks x 1024 thr = 16 waves/CU = 4 waves/SIMD. Wave w: column slot w>>1, m-half w&1 ->
// each wave owns 16 COMPLETE q-rows of one doc column (fr-build partitioned, no cross-wave
// combine). 16 cols/block (t4 in {0,1}).
// A-frag: m=lane&15, k=(lane>>4)*8+j.  B-frag: n=lane&15, same k.
// C/D: col=lane&15, row=(lane>>4)*4+reg  [m89/m91-verified].
__global__ __launch_bounds__(1024)
void main_kernel(const float* __restrict__ Aq, const short* __restrict__ Bws,
                 const float* __restrict__ W1cdf, const short* __restrict__ W2t,
                 const float* __restrict__ b2, const float* __restrict__ W3,
                 const float* __restrict__ b3, const float* __restrict__ sparse,
                 const float* __restrict__ dense_in, float* __restrict__ out_final){
    __shared__ __align__(16) short lw[73728];        // 147,456 B  W2 bf16 (16x16x32 frag order)
    __shared__ __align__(16) float lcd[768];         //   3,072 B  [0..383]=W1c, [384..767]=W1d
    const int tid = threadIdx.x;

    #pragma unroll
    for (int i=0;i<9;i++){
        int c = tid + i*1024;                        // < 9216
        *(f32x4*)(lw + c*8) = *(const f32x4*)(W2t + c*8);
    }
    if (tid < 192)
        *(f32x4*)(lcd + tid*4) = *(const f32x4*)(W1cdf + tid*4);
    __syncthreads();                                 // only barrier in the kernel

    const int lane = tid & 63, w = tid >> 6;
    const int colslot = w >> 1, mhalf = w & 1;
    const int cl = lane & 15, g = lane >> 4;
    const int mrow = mhalf*16 + cl;                  // q-row of this lane's A-frag
    const int k8 = g*8;                              // k-offset within a K=32 step
    const float b3v = b3[0];
    const int dcol0 = blockIdx.x*16 + colslot;

    #pragma unroll 1
    for (int t4=0; t4<2; t4++){
        const int dcol = dcol0 + t4*8;
        const float dsv = dense_in[mrow*4096 + dcol];
        const float ssv = sparse[mrow*4096 + dcol];
        const f32x2 dsv2 = {dsv, dsv}, ssv2 = {ssv, ssv};

        f32x4 acc[12];
        #pragma unroll
        for (int t=0;t<12;t++) acc[t] = (f32x4){0.f,0.f,0.f,0.f};

        const short* bp = Bws + dcol*384;
        const float* ap = Aq + mrow*384;

        // depth-2 prefetch (slot C = current step)
        bf16x8 bwC = *(const bf16x8*)(bp + k8);
        f32x4  aC0 = *(const f32x4*)(ap + k8);
        f32x4  aC1 = *(const f32x4*)(ap + k8 + 4);

        #pragma unroll 1
        for (int s=0; s<12; s++){
            const int kn = (s < 11) ? (s+1)*32 + k8 : k8;    // dummy wrap at tail
            const bf16x8 bwN = *(const bf16x8*)(bp + kn);
            const f32x4  aN0 = *(const f32x4*)(ap + kn);
            const f32x4  aN1 = *(const f32x4*)(ap + kn + 4);

            const int kf = s*32 + k8;
            const f32x4 wcA = *(const f32x4*)(lcd + kf);
            const f32x4 wcB = *(const f32x4*)(lcd + kf + 4);
            const f32x4 wdA = *(const f32x4*)(lcd + 384 + kf);
            const f32x4 wdB = *(const f32x4*)(lcd + 384 + kf + 4);

            u32x4 frw;
            { f32x2 h = {aC0[0] + bf2f(bwC[0]), aC0[1] + bf2f(bwC[1])};
              h += dsv2 * (f32x2){wcA[0],wcA[1]}; h += ssv2 * (f32x2){wdA[0],wdA[1]};
              frw[0] = cvt2(fmaxf(h[0],0.f), fmaxf(h[1],0.f)); }
            { f32x2 h = {aC0[2] + bf2f(bwC[2]), aC0[3] + bf2f(bwC[3])};
              h += dsv2 * (f32x2){wcA[2],wcA[3]}; h += ssv2 * (f32x2){wdA[2],wdA[3]};
              frw[1] = cvt2(fmaxf(h[0],0.f), fmaxf(h[1],0.f)); }
            { f32x2 h = {aC1[0] + bf2f(bwC[4]), aC1[1] + bf2f(bwC[5])};
              h += dsv2 * (f32x2){wcB[0],wcB[1]}; h += ssv2 * (f32x2){wdB[0],wdB[1]};
              frw[2] = cvt2(fmaxf(h[0],0.f), fmaxf(h[1],0.f)); }
            { f32x2 h = {aC1[2] + bf2f(bwC[6]), aC1[3] + bf2f(bwC[7])};
              h += dsv2 * (f32x2){wcB[2],wcB[3]}; h += ssv2 * (f32x2){wdB[2],wdB[3]};
              frw[3] = cvt2(fmaxf(h[0],0.f), fmaxf(h[1],0.f)); }
            const bf16x8 fr = __builtin_bit_cast(bf16x8, frw);

            // 12 n-tiles in groups of 3 (limits live bfr regs to 12)
            const short* lp = lw + s*6144 + lane*8;          // s*12*512 shorts
            #pragma unroll
            for (int tg=0; tg<4; tg++){
                const bf16x8 f0 = *(const bf16x8*)(lp + (tg*3+0)*512);
                const bf16x8 f1 = *(const bf16x8*)(lp + (tg*3+1)*512);
                const bf16x8 f2 = *(const bf16x8*)(lp + (tg*3+2)*512);
                acc[tg*3+0] = __builtin_amdgcn_mfma_f32_16x16x32_bf16(fr, f0, acc[tg*3+0], 0, 0, 0);
                acc[tg*3+1] = __builtin_amdgcn_mfma_f32_16x16x32_bf16(fr, f1, acc[tg*3+1], 0, 0, 0);
                acc[tg*3+2] = __builtin_amdgcn_mfma_f32_16x16x32_bf16(fr, f2, acc[tg*3+2], 0, 0, 0);
            }
            bwC = bwN; aC0 = aN0; aC1 = aN1;
        }

        // layer 3: this lane covers n = t*16+cl for rows g*4+r (+mhalf*16)
        float p0=0.f, p1=0.f, p2=0.f, p3=0.f;
        #pragma unroll
        for (int t=0;t<12;t++){
            const int n = t*16 + cl;
            const float b2v = b2[n];
            const float w3v = W3[n];
            p0 += fmaxf(acc[t][0] + b2v, 0.0f) * w3v;
            p1 += fmaxf(acc[t][1] + b2v, 0.0f) * w3v;
            p2 += fmaxf(acc[t][2] + b2v, 0.0f) * w3v;
            p3 += fmaxf(acc[t][3] + b2v, 0.0f) * w3v;
        }
        // reduce over the 16 lanes of this g-group (masks 1..8 stay within the group)
        #pragma unroll
        for (int mask=1; mask<16; mask<<=1){
            p0 += __shfl_xor(p0, mask);
            p1 += __shfl_xor(p1, mask);
            p2 += __shfl_xor(p2, mask);
            p3 += __shfl_xor(p3, mask);
        }
        // lane cl<4 writes row mhalf*16 + g*4 + cl (static cndmask chain)
        float myp = p0;
        myp = (cl==1) ? p1 : myp;
        myp = (cl==2) ? p2 : myp;
        myp = (cl==3) ? p3 : myp;
        if (cl < 4){
            const int row = mhalf*16 + g*4 + cl;
            const float logit = myp + b3v;
            const float wgt = 1.0f/(1.0f + __expf(-logit));
            const float dd = dense_in[row*4096 + dcol];
            const float ss = sparse[row*4096 + dcol];
            out_final[row*4096 + dcol] = wgt*dd + (1.0f - wgt)*ss;
        }
    }
}

// ---------------------------------------------------------------- launch
extern "C" void kernel_launch(void* const* d_in, const int* in_sizes, int n_in,
                              void* d_out, int out_size, void* d_ws, size_t ws_size,
                              hipStream_t stream){
    const float* query  = (const float*)d_in[0];
    const float* doc    = (const float*)d_in[1];
    const float* sparse = (const float*)d_in[2];
    const float* W1     = (const float*)d_in[3];
    const float* b1     = (const float*)d_in[4];
    const float* W2     = (const float*)d_in[5];
    const float* b2     = (const float*)d_in[6];
    const float* W3     = (const float*)d_in[7];
    const float* b3     = (const float*)d_in[8];

    float* out_final  = (float*)d_out;                 // [32,4096]
    float* out_dense  = (float*)d_out + 131072;        // [32,4096]
    float* out_sparse = (float*)d_out + 262144;        // [32,4096]

    // workspace layout (16B-aligned), total 7,105,536 B
    short* Bws   = (short*)d_ws;                                  // 3,145,728 B  (bf16 [4096][384])
    float* Aq    = (float*)((char*)d_ws + 3145728);               //    49,152 B  (f32  [32][384])
    float* W1cdf = (float*)((char*)d_ws + 3194880);               //     3,072 B  (f32  [768])
    short* W2t   = (short*)((char*)d_ws + 3197952);               //   147,456 B  (bf16 tiled W2)
    short* W1t   = (short*)((char*)d_ws + 3345408);               //   589,824 B  (bf16 tiled W1a+W1b)
    short* docb  = (short*)((char*)d_ws + 3935232);               // 3,145,728 B  (bf16 [4096][384])
    short* qb16  = (short*)((char*)d_ws + 7080960);               //    24,576 B  (bf16 [32][384])

    hipLaunchKernelGGL(pre0_kernel, dim3(174), dim3(256), 0, stream,
                       query, doc, W1, W2, W1t, docb, qb16, W1cdf, W2t);
    hipLaunchKernelGGL(pre1_kernel, dim3(258), dim3(256), 0, stream,
                       docb, qb16, W1t, b1, sparse, Bws, Aq, out_dense, out_sparse);
    hipLaunchKernelGGL(main_kernel, dim3(256), dim3(1024), 0, stream,
                       Aq, Bws, W1cdf, W2t, b2, W3, b3, sparse, out_dense, out_final);
}